// Round 13
// baseline (53.432 us; speedup 1.0000x reference)
//
#include <hip/hip_runtime.h>

typedef __attribute__((ext_vector_type(8))) short bf16x8;
typedef __attribute__((ext_vector_type(4))) float f32x4;
typedef __attribute__((ext_vector_type(4))) unsigned u32x4;

#define B_    2048
#define S_    512

// ws layout (bytes)
#define OFF_WF1   0u          // Wfrag1[32 nt][4 ks][64 lane][8] bf16 = 131072
#define OFF_WF2   131072u     // Wfrag2[32][16][64][8] = 524288
#define OFF_WF3   655360u     // Wfrag3[32][16][64][8] = 524288
#define OFF_PREF  1179648u    // float pref[512][64] (50 used) = 131072
#define OFF_H1F   1310720u    // h1 frags [128 bt][16 ks][64][8] bf16 = 2097152
#define OFF_H2F   3407872u    // h2 frags, same = 2097152
#define OFF_EMBB  5505024u    // bf16 emb [50000][64] (one 128B line/row) = 6400000
#define WS_NEED   (OFF_EMBB + 6400000u)

__device__ __forceinline__ unsigned short f2bf(float f) {
    unsigned int u = __float_as_uint(f);
    u += 0x7FFFu + ((u >> 16) & 1u);          // round-to-nearest-even
    return (unsigned short)(u >> 16);
}

#define MFMA16(a, b, c) __builtin_amdgcn_mfma_f32_16x16x32_bf16((a), (b), (c), 0, 0, 0)

// ---------------- prep_convert: weights->fragment-order bf16, pos-prefix, emb
__global__ __launch_bounds__(256) void prep_convert(
    const float* __restrict__ W1, const float* __restrict__ W2,
    const float* __restrict__ W3,
    const float* __restrict__ post, const int* __restrict__ pos,
    const float* __restrict__ emb,
    unsigned short* __restrict__ ws, float* __restrict__ pref, int do_emb)
{
    const int bid = blockIdx.x;
    const int tid = threadIdx.x;

    if (bid < 144) {                      // ---- weight convert, 64x64 (k,n) tile
        __shared__ float tile[64][65];
        const float* src; unsigned short* dst;
        int k0, n0, Ksrc, ksTot;
        if (bid < 64)       { src=W2; dst=ws+OFF_WF2/2; k0=(bid>>3)*64; n0=(bid&7)*64; Ksrc=512; ksTot=16; }
        else if (bid < 128) { int b=bid-64;  src=W3; dst=ws+OFF_WF3/2; k0=(b>>3)*64; n0=(b&7)*64; Ksrc=512; ksTot=16; }
        else                { int b=bid-128; src=W1; dst=ws+OFF_WF1/2; k0=(b>>3)*64; n0=(b&7)*64; Ksrc=100; ksTot=4;  }

        const int c  = tid & 63;
        const int r4 = tid >> 6;
#pragma unroll
        for (int rr = 0; rr < 16; ++rr) {
            int r = rr*4 + r4;
            float v = 0.f;
            if (k0 + r < Ksrc) v = src[(size_t)(k0+r)*512 + n0 + c];
            tile[r][c] = v;
        }
        __syncthreads();
        for (int w = tid; w < 8*64; w += 256) {
            int lane = w & 63, ks_l = (w >> 6) & 1, nt_l = w >> 7;
            int kr = ks_l*32 + ((lane >> 4) << 3);
            int nc = nt_l*16 + (lane & 15);
            uint4 wv;
            wv.x = (unsigned)f2bf(tile[kr+0][nc]) | ((unsigned)f2bf(tile[kr+1][nc]) << 16);
            wv.y = (unsigned)f2bf(tile[kr+2][nc]) | ((unsigned)f2bf(tile[kr+3][nc]) << 16);
            wv.z = (unsigned)f2bf(tile[kr+4][nc]) | ((unsigned)f2bf(tile[kr+5][nc]) << 16);
            wv.w = (unsigned)f2bf(tile[kr+6][nc]) | ((unsigned)f2bf(tile[kr+7][nc]) << 16);
            int ntile = (n0 >> 4) + nt_l, ks = (k0 >> 5) + ks_l;
            ((uint4*)dst)[(size_t)(ntile*ksTot + ks)*64 + lane] = wv;
        }
    } else if (bid == 144) {              // ---- pos-prefix, 4 chunks x 128, batch-8
        __shared__ int   idx_s[512];
        __shared__ float csum[4][52];
        idx_s[tid]       = pos[tid];
        idx_s[tid + 256] = pos[tid + 256];
        __syncthreads();
        const int c = tid >> 6, d = tid & 63;
        if (d < 50) {
            float run = 0.f;
            for (int b8 = 0; b8 < 16; ++b8) {
                float t[8];
#pragma unroll
                for (int u = 0; u < 8; ++u)
                    t[u] = post[(size_t)idx_s[c*128 + b8*8 + u]*50 + d];
#pragma unroll
                for (int u = 0; u < 8; ++u) {
                    run += t[u];
                    pref[(size_t)(c*128 + b8*8 + u)*64 + d] = run;
                }
            }
            csum[c][d] = run;
        }
        __syncthreads();
        if (d < 50 && c > 0) {
            float off = 0.f;
            for (int cc = 0; cc < c; ++cc) off += csum[cc][d];
            for (int b8 = 0; b8 < 16; ++b8) {
                float t[8];
#pragma unroll
                for (int u = 0; u < 8; ++u)
                    t[u] = pref[(size_t)(c*128 + b8*8 + u)*64 + d];
#pragma unroll
                for (int u = 0; u < 8; ++u)
                    pref[(size_t)(c*128 + b8*8 + u)*64 + d] = t[u] + off;
            }
        }
    } else {                              // ---- emb fp32 -> bf16, coalesced float2, ILP-8
        if (!do_emb) return;
        unsigned* embw = (unsigned*)(ws + OFF_EMBB/2);
        const float2* e2 = (const float2*)emb;        // 1,250,000 float2; never crosses a row
        const unsigned q0 = (unsigned)(bid - 145) * 2048u + (unsigned)tid;
        float2 v[8];
#pragma unroll
        for (int u = 0; u < 8; ++u) {
            unsigned q = q0 + (unsigned)u*256u;
            v[u] = (q < 1250000u) ? e2[q] : (float2){0.f, 0.f};
        }
#pragma unroll
        for (int u = 0; u < 8; ++u) {
            unsigned q = q0 + (unsigned)u*256u;
            if (q < 1250000u) {
                unsigned r = q / 25u, c2 = q - r*25u;
                embw[(size_t)r*32u + c2] =
                    (unsigned)f2bf(v[u].x) | ((unsigned)f2bf(v[u].y) << 16);
            }
        }
    }
}

// ---------------- pooling gather helpers (r12) --------------------------------
__device__ __forceinline__ void acc_u32x4(float (&a)[8], u32x4 q) {
#pragma unroll
    for (int v = 0; v < 4; ++v) {
        a[2*v]   += __uint_as_float(q[v] << 16);
        a[2*v+1] += __uint_as_float(q[v] & 0xffff0000u);
    }
}

__device__ __forceinline__ void loadbatch(u32x4 (&q)[8], const u32x4* tbl,
    const unsigned short* idxr, int s0, int L, int tg, int dq)
{
#pragma unroll
    for (int u = 0; u < 8; ++u) {
        int s_ = s0 + u*8 + tg;
        u32x4 v = {0u, 0u, 0u, 0u};
        if (s_ < L)
            v = __builtin_nontemporal_load(&tbl[(size_t)idxr[s_]*8u + (unsigned)dq]);
        q[u] = v;
    }
}

// ---------------- pool_l1: pooling + layer 1, writes h1 fragments ------------
// 256 blocks x 512 thr; wave w pools row b0+w (8 lanes/token, deep-pipelined),
// computes L1 (K=128) for cols w*64..+63, transposes D->A-frag via per-wave
// LDS, writes half-masked h1 frag words. Also inits out[b] = bf.
template<int EMODE>
__global__ __launch_bounds__(512) void pool_l1(
    const float* __restrict__ emb, const int* __restrict__ seq,
    const int* __restrict__ seqlen, const unsigned short* __restrict__ ws_ro,
    unsigned short* __restrict__ ws_rw, const float* __restrict__ pref,
    const float* __restrict__ b1, const float* __restrict__ bfin,
    float* __restrict__ out)
{
    __shared__ __align__(16) unsigned short idx_s[8*512];     // 8 KB
    __shared__ __align__(16) unsigned short pooled_s[16*144]; // 4.6 KB
    __shared__ __align__(16) char tbuf[8*2304];               // 18.4 KB

    const int tid  = threadIdx.x;
    const int wave = tid >> 6;
    const int lane = tid & 63;
    const int row  = lane & 15;
    const int kq   = lane >> 4;
    const int blk  = blockIdx.x;
    const int b0   = blk * 8;

    const unsigned short* WF1 = ws_ro + OFF_WF1 / 2;

    for (int i = tid; i < 8*512; i += 512)
        idx_s[i] = (unsigned short)seq[(size_t)b0 * S_ + i];
    for (int i = tid; i < 16*144; i += 512) pooled_s[i] = 0;
    if (tid < 16) out[b0*2 + tid] = bfin[tid & 1];

    // W1 fragments: coalesced, hide behind pooling
    bf16x8 w1f[4][4];
    {
        const bf16x8* bp1 = (const bf16x8*)WF1 + ((size_t)(wave*4) * 4 * 64) + lane;
#pragma unroll
        for (int ci = 0; ci < 4; ++ci)
#pragma unroll
            for (int ks = 0; ks < 4; ++ks) w1f[ci][ks] = bp1[(ci*4 + ks)*64];
    }
    __syncthreads();

    // ---- pooling (r12 deep-pipelined)
    const int L = seqlen[b0 + wave];
    const float Lf = (float)L;
    const unsigned short* idxr = idx_s + wave * 512;

    if (EMODE == 0) {
        const int tg = lane >> 3, dq = lane & 7;
        const u32x4* tbl = (const u32x4*)(ws_ro + OFF_EMBB / 2);
        float acc8[8];
#pragma unroll
        for (int j = 0; j < 8; ++j) acc8[j] = 0.f;

        u32x4 qA[8], qB[8];
        loadbatch(qA, tbl, idxr, 0,  L, tg, dq);
        loadbatch(qB, tbl, idxr, 64, L, tg, dq);
        int nit = (L + 63) >> 6;
        nit = (nit + 1) & ~1;
        for (int i = 0; i < nit; i += 2) {
#pragma unroll
            for (int u = 0; u < 8; ++u) acc_u32x4(acc8, qA[u]);
            loadbatch(qA, tbl, idxr, (i + 2) * 64, L, tg, dq);
#pragma unroll
            for (int u = 0; u < 8; ++u) acc_u32x4(acc8, qB[u]);
            loadbatch(qB, tbl, idxr, (i + 3) * 64, L, tg, dq);
        }
#pragma unroll
        for (int j = 0; j < 8; ++j) acc8[j] += __shfl_xor(acc8[j], 8);
#pragma unroll
        for (int j = 0; j < 8; ++j) acc8[j] += __shfl_xor(acc8[j], 16);
#pragma unroll
        for (int j = 0; j < 8; ++j) acc8[j] += __shfl_xor(acc8[j], 32);
        if (lane < 8) {
#pragma unroll
            for (int j = 0; j < 8; ++j) {
                int d = lane*8 + j;
                if (d < 50) pooled_s[wave*144 + d] = f2bf(acc8[j] / Lf);
            }
        }
    } else {
        float accE = 0.f;
        for (int s = 0; s < L; ++s) {
            int tok = idxr[s];
            if (lane < 50) accE += emb[(size_t)tok*50 + lane];
        }
        if (lane < 50) pooled_s[wave*144 + lane] = f2bf(accE / Lf);
    }
    if (lane < 50)
        pooled_s[wave*144 + 50 + lane] = f2bf(pref[(size_t)(L-1)*64 + lane] / Lf);
    __syncthreads();

    // ---- Layer 1 (K=128): rows 0..7 real (8..15 pad), cols wave*64..+63
    bf16x8 a1[4];
#pragma unroll
    for (int ks = 0; ks < 4; ++ks)
        a1[ks] = *(const bf16x8*)&pooled_s[row*144 + ks*32 + kq*8];

    char* tb = tbuf + wave*2304;
#pragma unroll
    for (int ci = 0; ci < 4; ++ci) {
        const float bb = b1[wave*64 + ci*16 + row];
        f32x4 acc = (f32x4){0.f,0.f,0.f,0.f};
#pragma unroll
        for (int ks = 0; ks < 4; ++ks) acc = MFMA16(a1[ks], w1f[ci][ks], acc);
#pragma unroll
        for (int r = 0; r < 4; ++r)
            *(unsigned short*)(tb + (kq*4 + r)*144 + (ci*16 + row)*2) =
                f2bf(fmaxf(acc[r] + bb, 0.f));
    }

    // read A-frag-order words (rows 0..7 local), masked global write
    unsigned short* h1f = ws_rw + OFF_H1F/2;
    const int bt = blk >> 1;
    const bool mine = ((row >> 3) == (blk & 1));
    const int lr = row & 7;
#pragma unroll
    for (int ksl = 0; ksl < 2; ++ksl) {
        bf16x8 wv = *(const bf16x8*)(tb + lr*144 + ksl*64 + kq*16);
        if (mine)
            ((bf16x8*)h1f)[(size_t)(bt*16 + wave*2 + ksl)*64 + lane] = wv;
    }
}

// ---------------- layer_kernel<L>: one 512x512 dense layer, 2D-tiled ---------
// grid 256 = 32 Mtiles(64 rows) x 8 Ntiles(64 cols); 8 waves = 4 mw x 2 nw.
// B slice (4 ntiles, 64KB, fragment-order = linear) staged via global_load_lds.
// L==2: write h2 frags (per-wave LDS D->A transpose). L==3: fused final
// projection: relu tile . Wf (fp32) -> shfl reduce -> atomicAdd into out.
template<int LAYER>
__global__ __launch_bounds__(512, 2) void layer_kernel(
    const unsigned short* __restrict__ ws_ro, unsigned short* __restrict__ ws_rw,
    const float* __restrict__ bias, const float* __restrict__ Wf,
    float* __restrict__ out)
{
    __shared__ __align__(16) char Bst[65536];
    __shared__ __align__(16) char tbuf[8*1536];   // 16 rows x 96B per wave

    const int tid  = threadIdx.x;
    const int wave = tid >> 6;
    const int lane = tid & 63;
    const int row  = lane & 15;
    const int kq   = lane >> 4;
    const int mb   = blockIdx.x >> 3;
    const int nb   = blockIdx.x & 7;
    const int mw   = wave >> 1;
    const int nw   = wave & 1;
    const int bt   = mb*4 + mw;

    const unsigned short* WF = ws_ro + (LAYER==2 ? OFF_WF2 : OFF_WF3)/2;
    const bf16x8* hin = (const bf16x8*)(ws_ro + (LAYER==2 ? OFF_H1F : OFF_H2F)/2);

    // stage B slice (ntiles nb*4..+3 = 64KB) linearly into LDS
    {
        const char* src = (const char*)WF + (size_t)(nb*4) * 16 * 1024;
#pragma unroll
        for (int it = 0; it < 8; ++it)
            __builtin_amdgcn_global_load_lds(
                (const __attribute__((address_space(1))) unsigned int*)(src + it*8192 + tid*16),
                (__attribute__((address_space(3))) unsigned int*)(Bst + it*8192 + tid*16),
                16, 0, 0);
    }

    // A fragments (issued pre-barrier; barrier drains vmcnt)
    bf16x8 a[16];
#pragma unroll
    for (int ks = 0; ks < 16; ++ks)
        a[ks] = hin[(size_t)(bt*16 + ks)*64 + lane];
    __syncthreads();

    f32x4 acc0 = (f32x4){0.f,0.f,0.f,0.f};
    f32x4 acc1 = (f32x4){0.f,0.f,0.f,0.f};
    const char* bp0 = Bst + (size_t)(nw*2 + 0)*16*1024 + lane*16;
    const char* bp1 = Bst + (size_t)(nw*2 + 1)*16*1024 + lane*16;
#pragma unroll
    for (int ks = 0; ks < 16; ++ks) {
        bf16x8 bv0 = *(const bf16x8*)(bp0 + ks*1024);
        bf16x8 bv1 = *(const bf16x8*)(bp1 + ks*1024);
        acc0 = MFMA16(a[ks], bv0, acc0);
        acc1 = MFMA16(a[ks], bv1, acc1);
    }

    const int nt0 = nb*4 + nw*2, nt1 = nt0 + 1;
    const float bb0 = bias[nt0*16 + row], bb1 = bias[nt1*16 + row];

    if (LAYER == 2) {
        char* tb = tbuf + wave*1536;
#pragma unroll
        for (int r = 0; r < 4; ++r) {
            *(unsigned short*)(tb + (kq*4 + r)*96 + row*2) =
                f2bf(fmaxf(acc0[r] + bb0, 0.f));
            *(unsigned short*)(tb + (kq*4 + r)*96 + (16 + row)*2) =
                f2bf(fmaxf(acc1[r] + bb1, 0.f));
        }
        bf16x8 wv = *(const bf16x8*)(tb + row*96 + kq*16);
        unsigned short* h2f = ws_rw + OFF_H2F/2;
        ((bf16x8*)h2f)[(size_t)(bt*16 + nb*2 + nw)*64 + lane] = wv;
    } else {
        float v0[4], v1[4];
#pragma unroll
        for (int r = 0; r < 4; ++r) {
            v0[r] = fmaxf(acc0[r] + bb0, 0.f);
            v1[r] = fmaxf(acc1[r] + bb1, 0.f);
        }
        const float2 wf0 = ((const float2*)Wf)[nt0*16 + row];
        const float2 wf1 = ((const float2*)Wf)[nt1*16 + row];
        float po[4][2];
#pragma unroll
        for (int r = 0; r < 4; ++r) {
            po[r][0] = v0[r]*wf0.x + v1[r]*wf1.x;
            po[r][1] = v0[r]*wf0.y + v1[r]*wf1.y;
        }
#pragma unroll
        for (int s = 1; s < 16; s <<= 1)
#pragma unroll
            for (int r = 0; r < 4; ++r) {
                po[r][0] += __shfl_xor(po[r][0], s);
                po[r][1] += __shfl_xor(po[r][1], s);
            }
        if (row == 0) {
#pragma unroll
            for (int r = 0; r < 4; ++r) {
                atomicAdd(&out[(size_t)(bt*16 + kq*4 + r)*2 + 0], po[r][0]);
                atomicAdd(&out[(size_t)(bt*16 + kq*4 + r)*2 + 1], po[r][1]);
            }
        }
    }
}

extern "C" void kernel_launch(void* const* d_in, const int* in_sizes, int n_in,
                              void* d_out, int out_size, void* d_ws, size_t ws_size,
                              hipStream_t stream)
{
    const float* emb    = (const float*)d_in[0];
    const float* post   = (const float*)d_in[1];
    const float* W1     = (const float*)d_in[2];
    const float* b1     = (const float*)d_in[3];
    const float* W2     = (const float*)d_in[4];
    const float* b2     = (const float*)d_in[5];
    const float* W3     = (const float*)d_in[6];
    const float* b3     = (const float*)d_in[7];
    const float* Wf     = (const float*)d_in[8];
    const float* bf     = (const float*)d_in[9];
    const int*   seq    = (const int*)d_in[10];
    const int*   seqlen = (const int*)d_in[11];
    const int*   pos    = (const int*)d_in[12];
    float*       out    = (float*)d_out;

    unsigned short* ws = (unsigned short*)d_ws;
    float* pref = (float*)((char*)d_ws + OFF_PREF);
    const int do_emb = (ws_size >= (size_t)WS_NEED) ? 1 : 0;

    const int prep_blocks = do_emb ? (145 + 611) : 145;
    prep_convert<<<prep_blocks, 256, 0, stream>>>(W1, W2, W3, post, pos, emb,
                                                  ws, pref, do_emb);
    if (do_emb)
        pool_l1<0><<<256, 512, 0, stream>>>(emb, seq, seqlen, ws, ws, pref,
                                            b1, bf, out);
    else
        pool_l1<1><<<256, 512, 0, stream>>>(emb, seq, seqlen, ws, ws, pref,
                                            b1, bf, out);
    layer_kernel<2><<<256, 512, 0, stream>>>(ws, ws, b2, Wf, out);
    layer_kernel<3><<<256, 512, 0, stream>>>(ws, ws, b3, Wf, out);
}

// Round 14
// 40.872 us; speedup vs baseline: 1.3073x; 1.3073x over previous
//
#include <hip/hip_runtime.h>

typedef __attribute__((ext_vector_type(8))) short bf16x8;
typedef __attribute__((ext_vector_type(4))) float f32x4;
typedef __attribute__((ext_vector_type(4))) unsigned u32x4;

#define B_    2048
#define S_    512

// ws layout (bytes)
#define OFF_WF1   0u          // Wfrag1[32 nt][4 ks][64 lane][8] bf16 = 131072
#define OFF_WF2   131072u     // Wfrag2[32][16][64][8] = 524288
#define OFF_WF3   655360u     // Wfrag3[32][16][64][8] = 524288
#define OFF_WFF   1179648u    // WfragF[16 ks][64][8]  = 16384 (cols>=2 zero)
#define OFF_PREF  1196032u    // float pref[512][64] (50 used)
#define OFF_EMBB  1327104u    // bf16 emb [50000][64] (one 128B line per row)
#define WS_NEED   (OFF_EMBB + 6400000u)

__device__ __forceinline__ unsigned short f2bf(float f) {
    unsigned int u = __float_as_uint(f);
    u += 0x7FFFu + ((u >> 16) & 1u);          // round-to-nearest-even
    return (unsigned short)(u >> 16);
}

#define MFMA16(a, b, c) __builtin_amdgcn_mfma_f32_16x16x32_bf16((a), (b), (c), 0, 0, 0)

// ---------------- prep_convert: weights->fragment-order bf16, pos-prefix, emb
// ALL d_ws stores are NONTEMPORAL: streamed past L2 so consumer kernels (on
// other XCDs) hit clean lines in L3 instead of cross-XCD dirty-L2 resolutions.
__global__ __launch_bounds__(256) void prep_convert(
    const float* __restrict__ W1, const float* __restrict__ W2,
    const float* __restrict__ W3, const float* __restrict__ Wf,
    const float* __restrict__ post, const int* __restrict__ pos,
    const float* __restrict__ emb,
    unsigned short* __restrict__ ws, float* __restrict__ pref, int do_emb)
{
    const int bid = blockIdx.x;
    const int tid = threadIdx.x;

    if (bid < 152) {                      // ---- weight convert, 64x64 (k,n) tile
        __shared__ float tile[64][65];
        const float* src; unsigned short* dst;
        int k0, n0, Ksrc, Nsrc, ksTot, nTiles;
        if (bid < 64)       { src=W2; dst=ws+OFF_WF2/2; k0=(bid>>3)*64; n0=(bid&7)*64; Ksrc=512; Nsrc=512; ksTot=16; nTiles=4; }
        else if (bid < 128) { int b=bid-64;  src=W3; dst=ws+OFF_WF3/2; k0=(b>>3)*64; n0=(b&7)*64; Ksrc=512; Nsrc=512; ksTot=16; nTiles=4; }
        else if (bid < 144) { int b=bid-128; src=W1; dst=ws+OFF_WF1/2; k0=(b>>3)*64; n0=(b&7)*64; Ksrc=100; Nsrc=512; ksTot=4;  nTiles=4; }
        else                { int b=bid-144; src=Wf; dst=ws+OFF_WFF/2; k0=b*64;      n0=0;        Ksrc=512; Nsrc=2;   ksTot=16; nTiles=1; }

        const int c  = tid & 63;
        const int r4 = tid >> 6;
#pragma unroll
        for (int rr = 0; rr < 16; ++rr) {
            int r = rr*4 + r4;
            float v = 0.f;
            if (k0 + r < Ksrc && n0 + c < Nsrc) v = src[(size_t)(k0+r)*Nsrc + n0 + c];
            tile[r][c] = v;
        }
        __syncthreads();
        const int nWords = nTiles * 2 * 64;
        for (int w = tid; w < nWords; w += 256) {
            int lane = w & 63, ks_l = (w >> 6) & 1, nt_l = w >> 7;
            int kr = ks_l*32 + ((lane >> 4) << 3);
            int nc = nt_l*16 + (lane & 15);
            u32x4 wv;
            wv[0] = (unsigned)f2bf(tile[kr+0][nc]) | ((unsigned)f2bf(tile[kr+1][nc]) << 16);
            wv[1] = (unsigned)f2bf(tile[kr+2][nc]) | ((unsigned)f2bf(tile[kr+3][nc]) << 16);
            wv[2] = (unsigned)f2bf(tile[kr+4][nc]) | ((unsigned)f2bf(tile[kr+5][nc]) << 16);
            wv[3] = (unsigned)f2bf(tile[kr+6][nc]) | ((unsigned)f2bf(tile[kr+7][nc]) << 16);
            int ntile = (n0 >> 4) + nt_l, ks = (k0 >> 5) + ks_l;
            __builtin_nontemporal_store(wv,
                (u32x4*)dst + (size_t)(ntile*ksTot + ks)*64 + lane);
        }
    } else if (bid == 152) {              // ---- pos-prefix, 4 chunks x 128, batch-8
        __shared__ int   idx_s[512];
        __shared__ float csum[4][52];
        __shared__ float pl[512][52];
        idx_s[tid]       = pos[tid];
        idx_s[tid + 256] = pos[tid + 256];
        __syncthreads();
        const int c = tid >> 6, d = tid & 63;
        if (d < 50) {
            float run = 0.f;
            for (int b8 = 0; b8 < 16; ++b8) {
                float t[8];
#pragma unroll
                for (int u = 0; u < 8; ++u)
                    t[u] = post[(size_t)idx_s[c*128 + b8*8 + u]*50 + d];
#pragma unroll
                for (int u = 0; u < 8; ++u) {
                    run += t[u];
                    pl[c*128 + b8*8 + u][d] = run;
                }
            }
            csum[c][d] = run;
        }
        __syncthreads();
        if (d < 50) {
            float off = 0.f;
            for (int cc = 0; cc < c; ++cc) off += csum[cc][d];
            for (int s = c*128; s < c*128 + 128; ++s)
                __builtin_nontemporal_store(pl[s][d] + off,
                                            &pref[(size_t)s*64 + d]);
        }
    } else {                              // ---- emb fp32 -> bf16, coalesced float2, ILP-8
        if (!do_emb) return;
        unsigned* embw = (unsigned*)(ws + OFF_EMBB/2);
        const float2* e2 = (const float2*)emb;        // 1,250,000 float2; never crosses a row
        const unsigned q0 = (unsigned)(bid - 153) * 2048u + (unsigned)tid;
        float2 v[8];
#pragma unroll
        for (int u = 0; u < 8; ++u) {
            unsigned q = q0 + (unsigned)u*256u;
            v[u] = (q < 1250000u) ? e2[q] : (float2){0.f, 0.f};
        }
#pragma unroll
        for (int u = 0; u < 8; ++u) {
            unsigned q = q0 + (unsigned)u*256u;
            if (q < 1250000u) {
                unsigned r = q / 25u, c2 = q - r*25u;
                __builtin_nontemporal_store(
                    (unsigned)f2bf(v[u].x) | ((unsigned)f2bf(v[u].y) << 16),
                    &embw[(size_t)r*32u + c2]);
            }
        }
    }
}

// ---------------- pooling gather helpers (r12) --------------------------------
__device__ __forceinline__ void acc_u32x4(float (&a)[8], u32x4 q) {
#pragma unroll
    for (int v = 0; v < 4; ++v) {
        a[2*v]   += __uint_as_float(q[v] << 16);
        a[2*v+1] += __uint_as_float(q[v] & 0xffff0000u);
    }
}

__device__ __forceinline__ void loadbatch(u32x4 (&q)[8], const u32x4* tbl,
    const unsigned short* idxr, int s0, int L, int tg, int dq)
{
#pragma unroll
    for (int u = 0; u < 8; ++u) {
        int s_ = s0 + u*8 + tg;
        u32x4 v = {0u, 0u, 0u, 0u};
        if (s_ < L)
            v = __builtin_nontemporal_load(&tbl[(size_t)idxr[s_]*8u + (unsigned)dq]);
        q[u] = v;
    }
}

// ---------------- MFMA helpers (swizzled LDS h-tiles, verified r2-r12) -------
__device__ __forceinline__ void load_afrags(bf16x8 (&a)[16],
    const unsigned short* h, int row, int kq)
{
#pragma unroll
    for (int ks = 0; ks < 16; ++ks)
        a[ks] = *(const bf16x8*)((const char*)h +
                  (((unsigned)(row * 1024 + ks * 64 + kq * 16)) ^ ((row & 7) << 4)));
}

__device__ __forceinline__ void store_h(unsigned short* h, const f32x4 (&acc)[4],
    const float (&bb)[4], int wave, int row, int kq)
{
#pragma unroll
    for (int nt = 0; nt < 4; ++nt) {
        int c = wave*64 + nt*16 + row;
#pragma unroll
        for (int r4 = 0; r4 < 4; ++r4) {
            int hrow = kq*4 + r4;
            unsigned base = hrow * 1024;
            *(unsigned short*)((char*)h + ((base + c*2) ^ ((hrow & 7) << 4))) =
                f2bf(fmaxf(acc[nt][r4] + bb[nt], 0.f));
        }
    }
}

// one 512x512 layer: wave owns ntiles wave*4..+3; coalesced fragment loads,
// double-buffered bv arrays, no barriers inside.
__device__ __forceinline__ void layer512(
    const bf16x8 (&a)[16], const unsigned short* __restrict__ Wfrag,
    const float* __restrict__ bias, unsigned short* hout,
    int wave, int row, int kq, int lane)
{
    const bf16x8* bp = (const bf16x8*)Wfrag + ((size_t)(wave*4) * 16 * 64) + lane;
    float bb[4];
#pragma unroll
    for (int nt = 0; nt < 4; ++nt) bb[nt] = bias[wave*64 + nt*16 + row];

    bf16x8 bvA[16], bvB[16];
#pragma unroll
    for (int ks = 0; ks < 16; ++ks) bvA[ks] = bp[(0*16 + ks)*64];
#pragma unroll
    for (int ks = 0; ks < 16; ++ks) bvB[ks] = bp[(1*16 + ks)*64];

    f32x4 acc[4];
    acc[0] = (f32x4){0.f,0.f,0.f,0.f};
#pragma unroll
    for (int ks = 0; ks < 16; ++ks) acc[0] = MFMA16(a[ks], bvA[ks], acc[0]);
#pragma unroll
    for (int ks = 0; ks < 16; ++ks) bvA[ks] = bp[(2*16 + ks)*64];

    acc[1] = (f32x4){0.f,0.f,0.f,0.f};
#pragma unroll
    for (int ks = 0; ks < 16; ++ks) acc[1] = MFMA16(a[ks], bvB[ks], acc[1]);
#pragma unroll
    for (int ks = 0; ks < 16; ++ks) bvB[ks] = bp[(3*16 + ks)*64];

    acc[2] = (f32x4){0.f,0.f,0.f,0.f};
#pragma unroll
    for (int ks = 0; ks < 16; ++ks) acc[2] = MFMA16(a[ks], bvA[ks], acc[2]);
    acc[3] = (f32x4){0.f,0.f,0.f,0.f};
#pragma unroll
    for (int ks = 0; ks < 16; ++ks) acc[3] = MFMA16(a[ks], bvB[ks], acc[3]);

    store_h(hout, acc, bb, wave, row, kq);
}

// ---------------- dan_fused: pooling + 4-layer MFMA MLP (r12 structure) ------
template<int EMODE>     // 0 = padded bf16 table in ws, 1 = fallback fp32
__global__ __launch_bounds__(512) void dan_fused(
    const float* __restrict__ emb, const int* __restrict__ seq,
    const int* __restrict__ seqlen, const unsigned short* __restrict__ ws_ro,
    const float* __restrict__ pref,
    const float* __restrict__ b1, const float* __restrict__ b2,
    const float* __restrict__ b3, const float* __restrict__ bfin,
    float* __restrict__ out)
{
    __shared__ __align__(16) unsigned short idx_s[8*512];     // 8 KB
    __shared__ __align__(16) unsigned short pooled_s[16*144]; // 4.6 KB
    __shared__ __align__(16) unsigned short hA[8192];         // 16 KB
    __shared__ __align__(16) unsigned short hB[8192];         // 16 KB

    const int tid  = threadIdx.x;
    const int wave = tid >> 6;
    const int lane = tid & 63;
    const int row  = lane & 15;
    const int kq   = lane >> 4;
    const int b0   = blockIdx.x * 8;

    const unsigned short* WF1 = ws_ro + OFF_WF1 / 2;
    const unsigned short* WF2 = ws_ro + OFF_WF2 / 2;
    const unsigned short* WF3 = ws_ro + OFF_WF3 / 2;
    const unsigned short* WFF = ws_ro + OFF_WFF / 2;

    for (int i = tid; i < 8*512; i += 512)
        idx_s[i] = (unsigned short)seq[(size_t)b0 * S_ + i];
    for (int i = tid; i < 16*144; i += 512) pooled_s[i] = 0;

    // W1 fragments: 16 coalesced 16B loads per wave (hide behind pooling)
    bf16x8 w1f[4][4];
    {
        const bf16x8* bp1 = (const bf16x8*)WF1 + ((size_t)(wave*4) * 4 * 64) + lane;
#pragma unroll
        for (int ci = 0; ci < 4; ++ci)
#pragma unroll
            for (int ks = 0; ks < 4; ++ks) w1f[ci][ks] = bp1[(ci*4 + ks)*64];
    }
    __syncthreads();

    // ---- pooling
    const int L = seqlen[b0 + wave];
    const float Lf = (float)L;
    const unsigned short* idxr = idx_s + wave * 512;

    if (EMODE == 0) {
        const int tg = lane >> 3, dq = lane & 7;      // token slot / 16B chunk
        const u32x4* tbl = (const u32x4*)(ws_ro + OFF_EMBB / 2);
        float acc8[8];
#pragma unroll
        for (int j = 0; j < 8; ++j) acc8[j] = 0.f;

        u32x4 qA[8], qB[8];
        loadbatch(qA, tbl, idxr, 0,  L, tg, dq);
        loadbatch(qB, tbl, idxr, 64, L, tg, dq);
        int nit = (L + 63) >> 6;
        nit = (nit + 1) & ~1;                         // even -> static A/B pairing
        for (int i = 0; i < nit; i += 2) {
#pragma unroll
            for (int u = 0; u < 8; ++u) acc_u32x4(acc8, qA[u]);
            loadbatch(qA, tbl, idxr, (i + 2) * 64, L, tg, dq);
#pragma unroll
            for (int u = 0; u < 8; ++u) acc_u32x4(acc8, qB[u]);
            loadbatch(qB, tbl, idxr, (i + 3) * 64, L, tg, dq);
        }
#pragma unroll
        for (int j = 0; j < 8; ++j) acc8[j] += __shfl_xor(acc8[j], 8);
#pragma unroll
        for (int j = 0; j < 8; ++j) acc8[j] += __shfl_xor(acc8[j], 16);
#pragma unroll
        for (int j = 0; j < 8; ++j) acc8[j] += __shfl_xor(acc8[j], 32);
        if (lane < 8) {
#pragma unroll
            for (int j = 0; j < 8; ++j) {
                int d = lane*8 + j;
                if (d < 50) pooled_s[wave*144 + d] = f2bf(acc8[j] / Lf);
            }
        }
    } else {
        float accE = 0.f;
        for (int s = 0; s < L; ++s) {
            int tok = idxr[s];
            if (lane < 50) accE += emb[(size_t)tok*50 + lane];
        }
        if (lane < 50) pooled_s[wave*144 + lane] = f2bf(accE / Lf);
    }
    if (lane < 50)
        pooled_s[wave*144 + 50 + lane] = f2bf(pref[(size_t)(L-1)*64 + lane] / Lf);
    __syncthreads();

    // ---- Layer 1 (K=128) from pooled_s, weights in regs
    {
        bf16x8 a1[4];
#pragma unroll
        for (int ks = 0; ks < 4; ++ks)
            a1[ks] = *(const bf16x8*)&pooled_s[row*144 + ks*32 + kq*8];
        f32x4 acc[4];
        float bb[4];
#pragma unroll
        for (int ci = 0; ci < 4; ++ci) {
            bb[ci] = b1[wave*64 + ci*16 + row];
            acc[ci] = (f32x4){0.f,0.f,0.f,0.f};
#pragma unroll
            for (int ks = 0; ks < 4; ++ks) acc[ci] = MFMA16(a1[ks], w1f[ci][ks], acc[ci]);
        }
        store_h(hA, acc, bb, wave, row, kq);
    }
    __syncthreads();

    // ---- Layer 2 (K=512): hA -> hB
    bf16x8 a[16];
    load_afrags(a, hA, row, kq);
    layer512(a, WF2, b2, hB, wave, row, kq, lane);
    __syncthreads();

    // ---- Layer 3 (K=512): hB -> hA
    load_afrags(a, hB, row, kq);
    layer512(a, WF3, b3, hA, wave, row, kq, lane);
    __syncthreads();

    // ---- Final (K=512, N padded 2->16): wave 0 only
    if (wave == 0) {
        load_afrags(a, hA, row, kq);
        const bf16x8* bpf = (const bf16x8*)WFF + lane;
        f32x4 accf = {0.f, 0.f, 0.f, 0.f};
#pragma unroll
        for (int ks = 0; ks < 16; ++ks) {
            bf16x8 bv = bpf[ks*64];
            accf = MFMA16(a[ks], bv, accf);
        }
        if (row < 2 && kq < 2) {
            float bb = bfin[row];
#pragma unroll
            for (int r4 = 0; r4 < 4; ++r4) {
                int m = kq*4 + r4;                   // real rows 0..7
                out[(size_t)(b0 + m) * 2 + row] = accf[r4] + bb;
            }
        }
    }
}

extern "C" void kernel_launch(void* const* d_in, const int* in_sizes, int n_in,
                              void* d_out, int out_size, void* d_ws, size_t ws_size,
                              hipStream_t stream)
{
    const float* emb    = (const float*)d_in[0];
    const float* post   = (const float*)d_in[1];
    const float* W1     = (const float*)d_in[2];
    const float* b1     = (const float*)d_in[3];
    const float* W2     = (const float*)d_in[4];
    const float* b2     = (const float*)d_in[5];
    const float* W3     = (const float*)d_in[6];
    const float* b3     = (const float*)d_in[7];
    const float* Wf     = (const float*)d_in[8];
    const float* bf     = (const float*)d_in[9];
    const int*   seq    = (const int*)d_in[10];
    const int*   seqlen = (const int*)d_in[11];
    const int*   pos    = (const int*)d_in[12];
    float*       out    = (float*)d_out;

    unsigned short* ws = (unsigned short*)d_ws;
    float* pref = (float*)((char*)d_ws + OFF_PREF);
    const int do_emb = (ws_size >= (size_t)WS_NEED) ? 1 : 0;

    const int prep_blocks = do_emb ? (153 + 611) : 153;
    prep_convert<<<prep_blocks, 256, 0, stream>>>(W1, W2, W3, Wf, post, pos, emb,
                                                  ws, pref, do_emb);
    if (do_emb)
        dan_fused<0><<<B_ / 8, 512, 0, stream>>>(emb, seq, seqlen, ws, pref,
                                                 b1, b2, b3, bf, out);
    else
        dan_fused<1><<<B_ / 8, 512, 0, stream>>>(emb, seq, seqlen, ws, pref,
                                                 b1, b2, b3, bf, out);
}